// Round 6
// baseline (800.141 us; speedup 1.0000x reference)
//
#include <hip/hip_runtime.h>
#include <hip/hip_bf16.h>

#define Mdim 4096
#define Kdim 4096
#define Ndim 12288

typedef __attribute__((ext_vector_type(8))) short short8;
typedef __attribute__((ext_vector_type(4))) float floatx4;
typedef __attribute__((ext_vector_type(4))) int intx4;
typedef __attribute__((ext_vector_type(4))) unsigned short ushortx4;
typedef __attribute__((ext_vector_type(8))) unsigned short ushortx8;

static __device__ __forceinline__ unsigned short f2bf(float x) {
    __hip_bfloat16 h = __float2bfloat16(x);
    return __builtin_bit_cast(unsigned short, h);
}

// async 16B global -> LDS (LDS dst = wave-uniform base + lane*16)
static __device__ __forceinline__ void gload_lds16(const unsigned short* g, unsigned short* l) {
    __builtin_amdgcn_global_load_lds(
        (const __attribute__((address_space(1))) unsigned int*)g,
        (__attribute__((address_space(3))) unsigned int*)l,
        16, 0, 0);
}

// ---------------- Pre-pass 1: Q[k][n] int32 codes -> Wt[n][k] bf16 -----------
__global__ void __launch_bounds__(256)
dequant_transpose(const int* __restrict__ Q, const float* __restrict__ S,
                  const float* __restrict__ Z, unsigned short* __restrict__ Wt)
{
    __shared__ unsigned short Ls[64][72];
    const int t     = threadIdx.x;
    const int kbase = blockIdx.x * 256;
    const int n0    = blockIdx.y * 64;
    const int tn = t & 15, tk = t >> 4;
    const int nc = tn * 4;
    const int n_out  = t >> 2;
    const int kc_out = (t & 3) * 16;

    #pragma unroll
    for (int s = 0; s < 4; ++s) {
        const int k0 = kbase + s * 64;
        const int g  = k0 >> 6;
        const floatx4 s4 = *reinterpret_cast<const floatx4*>(&S[(size_t)g * Ndim + n0 + nc]);
        const floatx4 z4 = *reinterpret_cast<const floatx4*>(&Z[(size_t)g * Ndim + n0 + nc]);
        intx4 q[4];
        #pragma unroll
        for (int r = 0; r < 4; ++r)
            q[r] = *reinterpret_cast<const intx4*>(&Q[(size_t)(k0 + tk * 4 + r) * Ndim + n0 + nc]);
        if (s) __syncthreads();
        #pragma unroll
        for (int j = 0; j < 4; ++j) {
            const float sv = s4[j], zv = z4[j];
            ushortx4 w;
            w.x = f2bf(fmaf((float)q[0][j], sv, zv));
            w.y = f2bf(fmaf((float)q[1][j], sv, zv));
            w.z = f2bf(fmaf((float)q[2][j], sv, zv));
            w.w = f2bf(fmaf((float)q[3][j], sv, zv));
            *reinterpret_cast<ushortx4*>(&Ls[nc + j][tk * 4]) = w;
        }
        __syncthreads();
        const ushortx8 a = *reinterpret_cast<const ushortx8*>(&Ls[n_out][kc_out]);
        const ushortx8 b = *reinterpret_cast<const ushortx8*>(&Ls[n_out][kc_out + 8]);
        unsigned short* dst = &Wt[(size_t)(n0 + n_out) * Kdim + k0 + kc_out];
        *reinterpret_cast<ushortx8*>(dst)     = a;
        *reinterpret_cast<ushortx8*>(dst + 8) = b;
    }
}

// ---------------- Pre-pass 2: X fp32 -> bf16 ---------------------------------
__global__ void __launch_bounds__(256)
xconv(const float* __restrict__ X, unsigned short* __restrict__ Xw)
{
    const size_t i = ((size_t)blockIdx.x * 256 + threadIdx.x) * 8;
    const floatx4 a = *reinterpret_cast<const floatx4*>(&X[i]);
    const floatx4 b = *reinterpret_cast<const floatx4*>(&X[i + 4]);
    ushortx8 w;
    w[0] = f2bf(a.x); w[1] = f2bf(a.y); w[2] = f2bf(a.z); w[3] = f2bf(a.w);
    w[4] = f2bf(b.x); w[5] = f2bf(b.y); w[6] = f2bf(b.z); w[7] = f2bf(b.w);
    *reinterpret_cast<ushortx8*>(&Xw[i]) = w;
}

// ---------------- Main GEMM: 256x256x64, 8-wave, deep-drain pipeline ---------
// R5 bug (deterministic absmax 706, identical R4/R5): phi4 read bB'(u+1) into
// the bB registers BEFORE MFMA_Q(afB,bB) -> Q4 consumed tile u+1's B-N23
// fragments. Register dataflow, not a race. FIX: Q4's MFMAs issue BEFORE the
// bB' read (restores R2's ordering). afA'/bA' pre-reads are safe: those regs
// are dead at their overwrite points (audited).
// FIFO drains (steady state, entering tile u with 8 outstanding = B(u+1),A(u+1)):
//   phi2-end vmcnt(8): queue [B+1h0,B+1h1,A+1h0,A+1h1,B+2h0,B+2h1] -> drains B(u+1)
//   phi3-end vmcnt(8): queue [A+1h0,A+1h1,B+2h0,B+2h1,A+2h0,A+2h1] -> drains A(u+1)
// Every drained load is 4-5 phases old. Tail u==NT-2: vmcnt(4) / vmcnt(0).
// Explicit lgkmcnt(0) before every phase-end barrier: runtime write-after-read
// guard for the LDS regions the next phases' DMA overwrites.

#define STAGE_A(c, kt, h) do { \
    const unsigned short* sp_ = A + aoff + (size_t)((h) * 128) * Kdim + (size_t)(kt) * 64; \
    unsigned short* dp_ = &As[c][((h) * 128 + wave * 16) * 64]; \
    gload_lds16(sp_, dp_); \
    gload_lds16(sp_ + (size_t)8 * Kdim, dp_ + 8 * 64); \
} while (0)

#define STAGE_B(c, kt, h) do { \
    const unsigned short* sp_ = B + boff + (size_t)((h) * 128) * Kdim + (size_t)(kt) * 64; \
    unsigned short* dp_ = &Bs[c][((h) * 128 + wave * 16) * 64]; \
    gload_lds16(sp_, dp_); \
    gload_lds16(sp_ + (size_t)8 * Kdim, dp_ + 8 * 64); \
} while (0)

#define LDA_(c, i, kh) (*reinterpret_cast<const short8*>( \
    &As[c][(wm + (i) * 16 + lrow) * 64 + (((kh) * 4 + quad) ^ lsw) * 8]))
#define LDB_(c, j, kh) (*reinterpret_cast<const short8*>( \
    &Bs[c][(wn + (j) * 16 + lrow) * 64 + (((kh) * 4 + quad) ^ lsw) * 8]))

#define SBAR()  __builtin_amdgcn_sched_barrier(0)

// 16 MFMA: all 8 k-half-0 first (independent), then 8 k-half-1 (dep distance 8)
#define MFMA_Q(AF, BF, IO, JO) do { \
    __builtin_amdgcn_s_setprio(1); \
    _Pragma("unroll") \
    for (int kh_ = 0; kh_ < 2; ++kh_) { \
        _Pragma("unroll") \
        for (int i_ = 0; i_ < 4; ++i_) { \
            _Pragma("unroll") \
            for (int j_ = 0; j_ < 2; ++j_) { \
                acc[(IO) + i_][(JO) + j_] = __builtin_amdgcn_mfma_f32_16x16x32_bf16( \
                    AF[i_][kh_], BF[j_][kh_], acc[(IO) + i_][(JO) + j_], 0, 0, 0); \
            } \
        } \
    } \
    __builtin_amdgcn_s_setprio(0); \
} while (0)

__global__ void __launch_bounds__(512, 2)
gemm_bf16_8p(const unsigned short* __restrict__ A, const unsigned short* __restrict__ B,
             const float* __restrict__ bias, float* __restrict__ O)
{
    __shared__ unsigned short As[2][256 * 64];   // 64 KiB
    __shared__ unsigned short Bs[2][256 * 64];   // 64 KiB

    constexpr int NT = Kdim / 64;                // 64 K-tiles

    // XCD-aware bijective swizzle (768 % 8 == 0), then 8-row-band grouping
    const int nblk = Ndim / 256;                 // 48
    const int cpx  = (Mdim / 256) * nblk / 8;    // 96 blocks per XCD
    const int bid  = blockIdx.x;
    const int swz  = (bid & 7) * cpx + (bid >> 3);
    const int gsz  = 8 * nblk;                   // 384
    const int grp  = swz / gsz;
    const int r    = swz % gsz;
    const int m0   = (grp * 8 + (r & 7)) * 256;
    const int n0   = (r >> 3) * 256;

    const int t    = threadIdx.x;
    const int wave = t >> 6;                     // 0..7
    const int lane = t & 63;
    const int wm   = (wave >> 2) * 128;          // 128-row half
    const int wn   = (wave & 3) * 64;            // 64-col quarter
    const int lrow = lane & 15;
    const int quad = lane >> 4;
    const int lsw  = lrow & 7;

    // staging: lane fills physical chunk (lane&7) of row (lane>>3) in an 8-row slab;
    // that chunk must hold logical k-chunk (lane&7)^(row&7)
    const int srow = lane >> 3;
    const int scol = ((lane & 7) ^ srow) * 8;
    const size_t aoff = (size_t)(m0 + wave * 16 + srow) * Kdim + scol;
    const size_t boff = (size_t)(n0 + wave * 16 + srow) * Kdim + scol;

    floatx4 acc[8][4];
    #pragma unroll
    for (int i = 0; i < 8; ++i)
        #pragma unroll
        for (int j = 0; j < 4; ++j)
            acc[i][j] = floatx4{0.f, 0.f, 0.f, 0.f};

    short8 afA[4][2];   // A-M0 frags of current tile
    short8 afB[4][2];   // A-M1 frags
    short8 bA[2][2];    // B-N01 frags
    short8 bB[2][2];    // B-N23 frags

    // -------- prologue: tile0 -> buf0 (8 loads), tile1 -> buf1 (8, order B,B,A,A)
    STAGE_A(0, 0, 0); STAGE_A(0, 0, 1);
    STAGE_B(0, 0, 0); STAGE_B(0, 0, 1);
    STAGE_B(1, 1, 0); STAGE_B(1, 1, 1);
    STAGE_A(1, 1, 0); STAGE_A(1, 1, 1);
    asm volatile("s_waitcnt vmcnt(8)" ::: "memory");   // tile0 resident; tile1 in flight
    __builtin_amdgcn_s_barrier();
    SBAR();
    #pragma unroll
    for (int i = 0; i < 4; ++i) { afA[i][0] = LDA_(0, i, 0); afA[i][1] = LDA_(0, i, 1); }
    #pragma unroll
    for (int j = 0; j < 2; ++j) { bA[j][0] = LDB_(0, j, 0); bA[j][1] = LDB_(0, j, 1); }
    #pragma unroll
    for (int j = 0; j < 2; ++j) { bB[j][0] = LDB_(0, j + 2, 0); bB[j][1] = LDB_(0, j + 2, 1); }
    asm volatile("s_waitcnt lgkmcnt(0)" ::: "memory");
    SBAR();
    __builtin_amdgcn_s_barrier();
    SBAR();

    for (int u = 0; u < NT; ++u) {
        const int c = u & 1, cn = c ^ 1;

        // ---- phi1: read afB(c); stage B(u+2)h0 -> Bs[c]; MFMA Q1 = afA x bA ----
        #pragma unroll
        for (int i = 0; i < 4; ++i) { afB[i][0] = LDA_(c, i + 4, 0); afB[i][1] = LDA_(c, i + 4, 1); }
        if (u + 2 < NT) STAGE_B(c, u + 2, 0);
        MFMA_Q(afA, bA, 0, 0);
        SBAR();
        asm volatile("s_waitcnt lgkmcnt(0)" ::: "memory");
        __builtin_amdgcn_s_barrier();
        SBAR();

        // ---- phi2: stage B(u+2)h1; MFMA Q2 = afB x bA; drain B(u+1) h0+h1 ----
        if (u + 2 < NT) STAGE_B(c, u + 2, 1);
        MFMA_Q(afB, bA, 4, 0);
        SBAR();
        if (u < NT - 2)       { asm volatile("s_waitcnt vmcnt(8) lgkmcnt(0)" ::: "memory"); }
        else if (u == NT - 2) { asm volatile("s_waitcnt vmcnt(4) lgkmcnt(0)" ::: "memory"); }
        else                  { asm volatile("s_waitcnt lgkmcnt(0)" ::: "memory"); }
        __builtin_amdgcn_s_barrier();
        SBAR();

        // ---- phi3: read bA'(cn) [bA dead: Q1/Q2 done]; stage A(u+2)h0+h1 -> As[c];
        //            MFMA Q3 = afA x bB; drain A(u+1) h0+h1 ----
        if (u + 1 < NT) {
            #pragma unroll
            for (int j = 0; j < 2; ++j) { bA[j][0] = LDB_(cn, j, 0); bA[j][1] = LDB_(cn, j, 1); }
        }
        if (u + 2 < NT) { STAGE_A(c, u + 2, 0); STAGE_A(c, u + 2, 1); }
        MFMA_Q(afA, bB, 0, 2);
        SBAR();
        if (u < NT - 2)       { asm volatile("s_waitcnt vmcnt(8) lgkmcnt(0)" ::: "memory"); }
        else if (u == NT - 2) { asm volatile("s_waitcnt vmcnt(0) lgkmcnt(0)" ::: "memory"); }
        else                  { asm volatile("s_waitcnt lgkmcnt(0)" ::: "memory"); }
        __builtin_amdgcn_s_barrier();
        SBAR();

        // ---- phi4: read afA'(cn) [afA dead: Q1/Q3 done]; MFMA Q4 = afB x bB;
        //            THEN read bB'(cn) [bB live until Q4 — the R3-R5 bug];
        //            lgkm drain; barrier ----
        if (u + 1 < NT) {
            #pragma unroll
            for (int i = 0; i < 4; ++i) { afA[i][0] = LDA_(cn, i, 0); afA[i][1] = LDA_(cn, i, 1); }
        }
        MFMA_Q(afB, bB, 4, 2);
        SBAR();
        if (u + 1 < NT) {
            #pragma unroll
            for (int j = 0; j < 2; ++j) { bB[j][0] = LDB_(cn, j + 2, 0); bB[j][1] = LDB_(cn, j + 2, 1); }
        }
        asm volatile("s_waitcnt lgkmcnt(0)" ::: "memory");
        SBAR();
        __builtin_amdgcn_s_barrier();
        SBAR();
    }

    // -------- epilogue --------
    #pragma unroll
    for (int j = 0; j < 4; ++j) {
        const int col = n0 + wn + j * 16 + lrow;
        const float bv = bias[col];
        #pragma unroll
        for (int i = 0; i < 8; ++i) {
            const int rbase = m0 + wm + i * 16 + quad * 4;
            #pragma unroll
            for (int rr = 0; rr < 4; ++rr)
                O[(size_t)(rbase + rr) * Ndim + col] = acc[i][j][rr] + bv;
        }
    }
}

// ---------------- Fallback (fused, ws-independent) ---------------------------
__global__ void __launch_bounds__(256)
w2a16_gemm_fb(const float* __restrict__ X, const int* __restrict__ Q,
              const float* __restrict__ S, const float* __restrict__ Z,
              const float* __restrict__ bias, float* __restrict__ O)
{
    __shared__ unsigned short Asf[128][72];
    __shared__ unsigned short Bsf[128][72];
    const int t  = threadIdx.x;
    const int n0 = blockIdx.x * 128;
    const int m0 = blockIdx.y * 128;
    const int wave = t >> 6, lane = t & 63;
    const int wm = (wave & 1) * 64, wn = (wave >> 1) * 64;
    const int lrow = lane & 15, quad = lane >> 4;
    floatx4 acc[4][4];
    #pragma unroll
    for (int i = 0; i < 4; ++i)
        #pragma unroll
        for (int j = 0; j < 4; ++j) acc[i][j] = floatx4{0.f, 0.f, 0.f, 0.f};
    const int a_row0 = t >> 4, a_c = (t & 15) * 4;
    const int b_n = t & 127, b_k0 = (t >> 7) * 32;
    for (int k0 = 0; k0 < Kdim; k0 += 64) {
        #pragma unroll
        for (int i = 0; i < 8; ++i) {
            const int row = a_row0 + i * 16;
            const floatx4 v = *reinterpret_cast<const floatx4*>(
                &X[(size_t)(m0 + row) * Kdim + k0 + a_c]);
            ushortx4 w;
            w.x = f2bf(v.x); w.y = f2bf(v.y); w.z = f2bf(v.z); w.w = f2bf(v.w);
            *reinterpret_cast<ushortx4*>(&Asf[row][a_c]) = w;
        }
        const int g = k0 >> 6;
        const float s = S[(size_t)g * Ndim + n0 + b_n];
        const float z = Z[(size_t)g * Ndim + n0 + b_n];
        #pragma unroll
        for (int i = 0; i < 8; ++i) {
            const int kk = b_k0 + i * 4;
            const int* qp = &Q[(size_t)(k0 + kk) * Ndim + n0 + b_n];
            ushortx4 w;
            w.x = f2bf(fmaf((float)qp[0],                s, z));
            w.y = f2bf(fmaf((float)qp[(size_t)Ndim],     s, z));
            w.z = f2bf(fmaf((float)qp[(size_t)2 * Ndim], s, z));
            w.w = f2bf(fmaf((float)qp[(size_t)3 * Ndim], s, z));
            *reinterpret_cast<ushortx4*>(&Bsf[b_n][kk]) = w;
        }
        __syncthreads();
        #pragma unroll
        for (int kk = 0; kk < 64; kk += 32) {
            short8 afv[4], bfv[4];
            #pragma unroll
            for (int i = 0; i < 4; ++i)
                afv[i] = *reinterpret_cast<const short8*>(&Asf[wm + i * 16 + lrow][kk + quad * 8]);
            #pragma unroll
            for (int j = 0; j < 4; ++j)
                bfv[j] = *reinterpret_cast<const short8*>(&Bsf[wn + j * 16 + lrow][kk + quad * 8]);
            #pragma unroll
            for (int i = 0; i < 4; ++i)
                #pragma unroll
                for (int j = 0; j < 4; ++j)
                    acc[i][j] = __builtin_amdgcn_mfma_f32_16x16x32_bf16(afv[i], bfv[j], acc[i][j], 0, 0, 0);
        }
        __syncthreads();
    }
    #pragma unroll
    for (int j = 0; j < 4; ++j) {
        const int col = n0 + wn + j * 16 + lrow;
        const float bv = bias[col];
        #pragma unroll
        for (int i = 0; i < 4; ++i) {
            const int rbase = m0 + wm + i * 16 + quad * 4;
            #pragma unroll
            for (int rr = 0; rr < 4; ++rr)
                O[(size_t)(rbase + rr) * Ndim + col] = acc[i][j][rr] + bv;
        }
    }
}

extern "C" void kernel_launch(void* const* d_in, const int* in_sizes, int n_in,
                              void* d_out, int out_size, void* d_ws, size_t ws_size,
                              hipStream_t stream) {
    const float* X  = (const float*)d_in[0];
    const int*   Q  = (const int*)d_in[1];
    const float* S  = (const float*)d_in[2];
    const float* Z  = (const float*)d_in[3];
    const float* Bi = (const float*)d_in[4];
    float* O = (float*)d_out;

    const size_t wt_bytes = (size_t)Kdim * Ndim * 2;
    const size_t xw_bytes = (size_t)Mdim * Kdim * 2;

    if (ws_size >= wt_bytes + xw_bytes) {
        unsigned short* Wt = (unsigned short*)d_ws;
        unsigned short* Xw = (unsigned short*)((char*)d_ws + wt_bytes);

        dim3 g1(Kdim / 256, Ndim / 64);                   // (16, 192)
        hipLaunchKernelGGL(dequant_transpose, g1, dim3(256), 0, stream, Q, S, Z, Wt);

        const int xblocks = (Mdim * Kdim) / (256 * 8);    // 8192
        hipLaunchKernelGGL(xconv, dim3(xblocks), dim3(256), 0, stream, X, Xw);

        const int nblocks = (Mdim / 256) * (Ndim / 256);  // 768
        hipLaunchKernelGGL(gemm_bf16_8p, dim3(nblocks), dim3(512), 0, stream, Xw, Wt, Bi, O);
    } else {
        dim3 grid(Ndim / 128, Mdim / 128);
        hipLaunchKernelGGL(w2a16_gemm_fb, grid, dim3(256), 0, stream, X, Q, S, Z, Bi, O);
    }
}

// Round 7
// 779.471 us; speedup vs baseline: 1.0265x; 1.0265x over previous
//
#include <hip/hip_runtime.h>
#include <hip/hip_bf16.h>

#define Mdim 4096
#define Kdim 4096
#define Ndim 12288

typedef __attribute__((ext_vector_type(8))) short short8;
typedef __attribute__((ext_vector_type(4))) float floatx4;
typedef __attribute__((ext_vector_type(4))) int intx4;
typedef __attribute__((ext_vector_type(4))) unsigned short ushortx4;
typedef __attribute__((ext_vector_type(8))) unsigned short ushortx8;

static __device__ __forceinline__ unsigned short f2bf(float x) {
    __hip_bfloat16 h = __float2bfloat16(x);
    return __builtin_bit_cast(unsigned short, h);
}

// async 16B global -> LDS (LDS dst = wave-uniform base + lane*16)
static __device__ __forceinline__ void gload_lds16(const unsigned short* g, unsigned short* l) {
    __builtin_amdgcn_global_load_lds(
        (const __attribute__((address_space(1))) unsigned int*)g,
        (__attribute__((address_space(3))) unsigned int*)l,
        16, 0, 0);
}

// ---------------- Pre-pass 1 v2: Q[k][n] int32 -> Wt[n][k] bf16 --------------
// v1 was latency-bound: 4 serial stages x (4 loads in flight -> 2 barriers) = 8
// barriers/block, ~4 outstanding loads. v2: per-stage LDS buffers (36.9 KB),
// ALL 16 intx4 + 8 scale/zp loads issued up front, ONE barrier, then all
// LDS reads + global stores. Identical index mapping and coalescing to v1.
__global__ void __launch_bounds__(256)
dequant_transpose(const int* __restrict__ Q, const float* __restrict__ S,
                  const float* __restrict__ Z, unsigned short* __restrict__ Wt)
{
    __shared__ unsigned short Ls[4][64][72];     // 4 stages, 36.9 KB
    const int t     = threadIdx.x;
    const int kbase = blockIdx.x * 256;
    const int n0    = blockIdx.y * 64;
    const int tn = t & 15, tk = t >> 4;
    const int nc = tn * 4;
    const int n_out  = t >> 2;
    const int kc_out = (t & 3) * 16;

    // ---- issue ALL global loads first (max MLP), convert + LDS-write per stage
    floatx4 s4[4], z4[4];
    intx4 q[4][4];
    #pragma unroll
    for (int s = 0; s < 4; ++s) {
        const int k0 = kbase + s * 64;
        const int g  = k0 >> 6;                  // GROUP == 64
        s4[s] = *reinterpret_cast<const floatx4*>(&S[(size_t)g * Ndim + n0 + nc]);
        z4[s] = *reinterpret_cast<const floatx4*>(&Z[(size_t)g * Ndim + n0 + nc]);
        #pragma unroll
        for (int r = 0; r < 4; ++r)
            q[s][r] = *reinterpret_cast<const intx4*>(
                &Q[(size_t)(k0 + tk * 4 + r) * Ndim + n0 + nc]);
    }
    #pragma unroll
    for (int s = 0; s < 4; ++s) {
        #pragma unroll
        for (int j = 0; j < 4; ++j) {
            const float sv = s4[s][j], zv = z4[s][j];
            ushortx4 w;
            w.x = f2bf(fmaf((float)q[s][0][j], sv, zv));
            w.y = f2bf(fmaf((float)q[s][1][j], sv, zv));
            w.z = f2bf(fmaf((float)q[s][2][j], sv, zv));
            w.w = f2bf(fmaf((float)q[s][3][j], sv, zv));
            *reinterpret_cast<ushortx4*>(&Ls[s][nc + j][tk * 4]) = w;
        }
    }
    __syncthreads();                             // the ONLY barrier
    #pragma unroll
    for (int s = 0; s < 4; ++s) {
        const ushortx8 a = *reinterpret_cast<const ushortx8*>(&Ls[s][n_out][kc_out]);
        const ushortx8 b = *reinterpret_cast<const ushortx8*>(&Ls[s][n_out][kc_out + 8]);
        unsigned short* dst = &Wt[(size_t)(n0 + n_out) * Kdim + kbase + s * 64 + kc_out];
        *reinterpret_cast<ushortx8*>(dst)     = a;
        *reinterpret_cast<ushortx8*>(dst + 8) = b;
    }
}

// ---------------- Pre-pass 2: X fp32 -> bf16 ---------------------------------
__global__ void __launch_bounds__(256)
xconv(const float* __restrict__ X, unsigned short* __restrict__ Xw)
{
    const size_t i = ((size_t)blockIdx.x * 256 + threadIdx.x) * 8;
    const floatx4 a = *reinterpret_cast<const floatx4*>(&X[i]);
    const floatx4 b = *reinterpret_cast<const floatx4*>(&X[i + 4]);
    ushortx8 w;
    w[0] = f2bf(a.x); w[1] = f2bf(a.y); w[2] = f2bf(a.z); w[3] = f2bf(a.w);
    w[4] = f2bf(b.x); w[5] = f2bf(b.y); w[6] = f2bf(b.z); w[7] = f2bf(b.w);
    *reinterpret_cast<ushortx8*>(&Xw[i]) = w;
}

// ---------------- Main GEMM: 256x256x64, 8-wave, rotated pre-read (R2) -------
// Best verified schedule (422 us, MfmaUtil 44%). Deep-drain variants (R6)
// were correct but slower -> the stall is LDS port/sync machinery, not vmcnt
// latency; keep R2.

#define STAGE_A(c, kt, h) do { \
    const unsigned short* sp_ = A + aoff + (size_t)((h) * 128) * Kdim + (size_t)(kt) * 64; \
    unsigned short* dp_ = &As[c][((h) * 128 + wave * 16) * 64]; \
    gload_lds16(sp_, dp_); \
    gload_lds16(sp_ + (size_t)8 * Kdim, dp_ + 8 * 64); \
} while (0)

#define STAGE_B(c, kt, h) do { \
    const unsigned short* sp_ = B + boff + (size_t)((h) * 128) * Kdim + (size_t)(kt) * 64; \
    unsigned short* dp_ = &Bs[c][((h) * 128 + wave * 16) * 64]; \
    gload_lds16(sp_, dp_); \
    gload_lds16(sp_ + (size_t)8 * Kdim, dp_ + 8 * 64); \
} while (0)

#define LDA_(c, i, kh) (*reinterpret_cast<const short8*>( \
    &As[c][(wm + (i) * 16 + lrow) * 64 + (((kh) * 4 + quad) ^ lsw) * 8]))
#define LDB_(c, j, kh) (*reinterpret_cast<const short8*>( \
    &Bs[c][(wn + (j) * 16 + lrow) * 64 + (((kh) * 4 + quad) ^ lsw) * 8]))

#define SBAR()  __builtin_amdgcn_sched_barrier(0)

// 16 MFMA: all 8 k-half-0 first (independent), then 8 k-half-1 (dep distance 8)
#define MFMA_Q(AF, BF, IO, JO) do { \
    __builtin_amdgcn_s_setprio(1); \
    _Pragma("unroll") \
    for (int kh_ = 0; kh_ < 2; ++kh_) { \
        _Pragma("unroll") \
        for (int i_ = 0; i_ < 4; ++i_) { \
            _Pragma("unroll") \
            for (int j_ = 0; j_ < 2; ++j_) { \
                acc[(IO) + i_][(JO) + j_] = __builtin_amdgcn_mfma_f32_16x16x32_bf16( \
                    AF[i_][kh_], BF[j_][kh_], acc[(IO) + i_][(JO) + j_], 0, 0, 0); \
            } \
        } \
    } \
    __builtin_amdgcn_s_setprio(0); \
} while (0)

__global__ void __launch_bounds__(512, 2)
gemm_bf16_8p(const unsigned short* __restrict__ A, const unsigned short* __restrict__ B,
             const float* __restrict__ bias, float* __restrict__ O)
{
    __shared__ unsigned short As[2][256 * 64];   // 64 KiB
    __shared__ unsigned short Bs[2][256 * 64];   // 64 KiB

    constexpr int NT = Kdim / 64;                // 64 K-tiles

    // XCD-aware bijective swizzle (768 % 8 == 0), then 8-row-band grouping
    const int nblk = Ndim / 256;                 // 48
    const int cpx  = (Mdim / 256) * nblk / 8;    // 96 blocks per XCD
    const int bid  = blockIdx.x;
    const int swz  = (bid & 7) * cpx + (bid >> 3);
    const int gsz  = 8 * nblk;                   // 384
    const int grp  = swz / gsz;
    const int r    = swz % gsz;
    const int m0   = (grp * 8 + (r & 7)) * 256;
    const int n0   = (r >> 3) * 256;

    const int t    = threadIdx.x;
    const int wave = t >> 6;                     // 0..7
    const int lane = t & 63;
    const int wm   = (wave >> 2) * 128;          // 128-row half
    const int wn   = (wave & 3) * 64;            // 64-col quarter
    const int lrow = lane & 15;
    const int quad = lane >> 4;
    const int lsw  = lrow & 7;

    // staging: lane fills physical chunk (lane&7) of row (lane>>3) in an 8-row slab;
    // that chunk must hold logical k-chunk (lane&7)^(row&7)
    const int srow = lane >> 3;
    const int scol = ((lane & 7) ^ srow) * 8;
    const size_t aoff = (size_t)(m0 + wave * 16 + srow) * Kdim + scol;
    const size_t boff = (size_t)(n0 + wave * 16 + srow) * Kdim + scol;

    floatx4 acc[8][4];
    #pragma unroll
    for (int i = 0; i < 8; ++i)
        #pragma unroll
        for (int j = 0; j < 4; ++j)
            acc[i][j] = floatx4{0.f, 0.f, 0.f, 0.f};

    short8 afA[4][2];   // A-M0 frags of current tile
    short8 afB[4][2];   // A-M1 frags
    short8 bA[2][2];    // B-N01 frags
    short8 bB[2][2];    // B-N23 frags

    // -------- prologue: stage A0,B0 (buf0), B1 (buf1), A1h0 (buf1) ----------
    STAGE_A(0, 0, 0); STAGE_A(0, 0, 1);
    STAGE_B(0, 0, 0); STAGE_B(0, 0, 1);
    STAGE_B(1, 1, 0); STAGE_B(1, 1, 1);
    STAGE_A(1, 1, 0);
    asm volatile("s_waitcnt vmcnt(2)" ::: "memory");   // A0,B0,B1 done; A1h0 in flight
    __builtin_amdgcn_s_barrier();
    SBAR();
    #pragma unroll
    for (int i = 0; i < 4; ++i) { afA[i][0] = LDA_(0, i, 0); afA[i][1] = LDA_(0, i, 1); }
    #pragma unroll
    for (int j = 0; j < 2; ++j) { bA[j][0] = LDB_(0, j, 0); bA[j][1] = LDB_(0, j, 1); }
    #pragma unroll
    for (int j = 0; j < 2; ++j) { bB[j][0] = LDB_(0, j + 2, 0); bB[j][1] = LDB_(0, j + 2, 1); }
    asm volatile("s_waitcnt lgkmcnt(0)" ::: "memory");
    SBAR();
    __builtin_amdgcn_s_barrier();
    SBAR();

    for (int u = 0; u < NT; ++u) {
        const int c = u & 1, cn = c ^ 1;

        // ---- phi1: read afB(c); stage A(u+1)h1 then B(u+2)h0; MFMA Q1 ----
        #pragma unroll
        for (int i = 0; i < 4; ++i) { afB[i][0] = LDA_(c, i + 4, 0); afB[i][1] = LDA_(c, i + 4, 1); }
        if (u + 1 < NT) STAGE_A(cn, u + 1, 1);
        if (u + 2 < NT) STAGE_B(c, u + 2, 0);
        MFMA_Q(afA, bA, 0, 0);
        SBAR();
        __builtin_amdgcn_s_barrier();
        SBAR();

        // ---- phi2: stage B(u+2)h1; MFMA Q2; counted vmcnt; barrier ----
        if (u + 2 < NT) STAGE_B(c, u + 2, 1);
        MFMA_Q(afB, bA, 4, 0);
        SBAR();
        if (u < NT - 2) { asm volatile("s_waitcnt vmcnt(4)" ::: "memory"); }
        else            { asm volatile("s_waitcnt vmcnt(0)" ::: "memory"); }
        __builtin_amdgcn_s_barrier();
        SBAR();

        // ---- phi3: pre-read bA'(u+1); MFMA Q3 ----
        if (u + 1 < NT) {
            #pragma unroll
            for (int j = 0; j < 2; ++j) { bA[j][0] = LDB_(cn, j, 0); bA[j][1] = LDB_(cn, j, 1); }
        }
        MFMA_Q(afA, bB, 0, 2);
        SBAR();
        __builtin_amdgcn_s_barrier();
        SBAR();

        // ---- phi4: pre-read afA'(u+1); stage A(u+2)h0; MFMA Q4; THEN read bB'; drain ----
        if (u + 1 < NT) {
            #pragma unroll
            for (int i = 0; i < 4; ++i) { afA[i][0] = LDA_(cn, i, 0); afA[i][1] = LDA_(cn, i, 1); }
        }
        if (u + 2 < NT) STAGE_A(c, u + 2, 0);
        MFMA_Q(afB, bB, 4, 2);
        SBAR();
        if (u + 1 < NT) {
            #pragma unroll
            for (int j = 0; j < 2; ++j) { bB[j][0] = LDB_(cn, j + 2, 0); bB[j][1] = LDB_(cn, j + 2, 1); }
        }
        asm volatile("s_waitcnt lgkmcnt(0)" ::: "memory");
        SBAR();
        __builtin_amdgcn_s_barrier();
        SBAR();
    }

    // -------- epilogue --------
    #pragma unroll
    for (int j = 0; j < 4; ++j) {
        const int col = n0 + wn + j * 16 + lrow;
        const float bv = bias[col];
        #pragma unroll
        for (int i = 0; i < 8; ++i) {
            const int rbase = m0 + wm + i * 16 + quad * 4;
            #pragma unroll
            for (int rr = 0; rr < 4; ++rr)
                O[(size_t)(rbase + rr) * Ndim + col] = acc[i][j][rr] + bv;
        }
    }
}

// ---------------- Fallback (fused, ws-independent) ---------------------------
__global__ void __launch_bounds__(256)
w2a16_gemm_fb(const float* __restrict__ X, const int* __restrict__ Q,
              const float* __restrict__ S, const float* __restrict__ Z,
              const float* __restrict__ bias, float* __restrict__ O)
{
    __shared__ unsigned short Asf[128][72];
    __shared__ unsigned short Bsf[128][72];
    const int t  = threadIdx.x;
    const int n0 = blockIdx.x * 128;
    const int m0 = blockIdx.y * 128;
    const int wave = t >> 6, lane = t & 63;
    const int wm = (wave & 1) * 64, wn = (wave >> 1) * 64;
    const int lrow = lane & 15, quad = lane >> 4;
    floatx4 acc[4][4];
    #pragma unroll
    for (int i = 0; i < 4; ++i)
        #pragma unroll
        for (int j = 0; j < 4; ++j) acc[i][j] = floatx4{0.f, 0.f, 0.f, 0.f};
    const int a_row0 = t >> 4, a_c = (t & 15) * 4;
    const int b_n = t & 127, b_k0 = (t >> 7) * 32;
    for (int k0 = 0; k0 < Kdim; k0 += 64) {
        #pragma unroll
        for (int i = 0; i < 8; ++i) {
            const int row = a_row0 + i * 16;
            const floatx4 v = *reinterpret_cast<const floatx4*>(
                &X[(size_t)(m0 + row) * Kdim + k0 + a_c]);
            ushortx4 w;
            w.x = f2bf(v.x); w.y = f2bf(v.y); w.z = f2bf(v.z); w.w = f2bf(v.w);
            *reinterpret_cast<ushortx4*>(&Asf[row][a_c]) = w;
        }
        const int g = k0 >> 6;
        const float s = S[(size_t)g * Ndim + n0 + b_n];
        const float z = Z[(size_t)g * Ndim + n0 + b_n];
        #pragma unroll
        for (int i = 0; i < 8; ++i) {
            const int kk = b_k0 + i * 4;
            const int* qp = &Q[(size_t)(k0 + kk) * Ndim + n0 + b_n];
            ushortx4 w;
            w.x = f2bf(fmaf((float)qp[0],                s, z));
            w.y = f2bf(fmaf((float)qp[(size_t)Ndim],     s, z));
            w.z = f2bf(fmaf((float)qp[(size_t)2 * Ndim], s, z));
            w.w = f2bf(fmaf((float)qp[(size_t)3 * Ndim], s, z));
            *reinterpret_cast<ushortx4*>(&Bsf[b_n][kk]) = w;
        }
        __syncthreads();
        #pragma unroll
        for (int kk = 0; kk < 64; kk += 32) {
            short8 afv[4], bfv[4];
            #pragma unroll
            for (int i = 0; i < 4; ++i)
                afv[i] = *reinterpret_cast<const short8*>(&Asf[wm + i * 16 + lrow][kk + quad * 8]);
            #pragma unroll
            for (int j = 0; j < 4; ++j)
                bfv[j] = *reinterpret_cast<const short8*>(&Bsf[wn + j * 16 + lrow][kk + quad * 8]);
            #pragma unroll
            for (int i = 0; i < 4; ++i)
                #pragma unroll
                for (int j = 0; j < 4; ++j)
                    acc[i][j] = __builtin_amdgcn_mfma_f32_16x16x32_bf16(afv[i], bfv[j], acc[i][j], 0, 0, 0);
        }
        __syncthreads();
    }
    #pragma unroll
    for (int j = 0; j < 4; ++j) {
        const int col = n0 + wn + j * 16 + lrow;
        const float bv = bias[col];
        #pragma unroll
        for (int i = 0; i < 4; ++i) {
            const int rbase = m0 + wm + i * 16 + quad * 4;
            #pragma unroll
            for (int rr = 0; rr < 4; ++rr)
                O[(size_t)(rbase + rr) * Ndim + col] = acc[i][j][rr] + bv;
        }
    }
}

extern "C" void kernel_launch(void* const* d_in, const int* in_sizes, int n_in,
                              void* d_out, int out_size, void* d_ws, size_t ws_size,
                              hipStream_t stream) {
    const float* X  = (const float*)d_in[0];
    const int*   Q  = (const int*)d_in[1];
    const float* S  = (const float*)d_in[2];
    const float* Z  = (const float*)d_in[3];
    const float* Bi = (const float*)d_in[4];
    float* O = (float*)d_out;

    const size_t wt_bytes = (size_t)Kdim * Ndim * 2;
    const size_t xw_bytes = (size_t)Mdim * Kdim * 2;

    if (ws_size >= wt_bytes + xw_bytes) {
        unsigned short* Wt = (unsigned short*)d_ws;
        unsigned short* Xw = (unsigned short*)((char*)d_ws + wt_bytes);

        dim3 g1(Kdim / 256, Ndim / 64);                   // (16, 192)
        hipLaunchKernelGGL(dequant_transpose, g1, dim3(256), 0, stream, Q, S, Z, Wt);

        const int xblocks = (Mdim * Kdim) / (256 * 8);    // 8192
        hipLaunchKernelGGL(xconv, dim3(xblocks), dim3(256), 0, stream, X, Xw);

        const int nblocks = (Mdim / 256) * (Ndim / 256);  // 768
        hipLaunchKernelGGL(gemm_bf16_8p, dim3(nblocks), dim3(512), 0, stream, Xw, Wt, Bi, O);
    } else {
        dim3 grid(Ndim / 128, Mdim / 128);
        hipLaunchKernelGGL(w2a16_gemm_fb, grid, dim3(256), 0, stream, X, Q, S, Z, Bi, O);
    }
}

// Round 8
// 763.819 us; speedup vs baseline: 1.0476x; 1.0205x over previous
//
#include <hip/hip_runtime.h>
#include <hip/hip_bf16.h>

#define Mdim 4096
#define Kdim 4096
#define Ndim 12288

typedef __attribute__((ext_vector_type(8))) short short8;
typedef __attribute__((ext_vector_type(4))) float floatx4;
typedef __attribute__((ext_vector_type(4))) int intx4;
typedef __attribute__((ext_vector_type(4))) unsigned short ushortx4;
typedef __attribute__((ext_vector_type(8))) unsigned short ushortx8;

static __device__ __forceinline__ unsigned short f2bf(float x) {
    __hip_bfloat16 h = __float2bfloat16(x);
    return __builtin_bit_cast(unsigned short, h);
}

// async 16B global -> LDS (LDS dst = wave-uniform base + lane*16)
static __device__ __forceinline__ void gload_lds16(const unsigned short* g, unsigned short* l) {
    __builtin_amdgcn_global_load_lds(
        (const __attribute__((address_space(1))) unsigned int*)g,
        (__attribute__((address_space(3))) unsigned int*)l,
        16, 0, 0);
}

// ---------------- Fused pre-pass: dequant+transpose AND xconv, ONE launch ----
// Blocks 0..3071: Q[k][n] int32 -> Wt[n][k] bf16 (v2 load/convert/LDS phase
//   kept verbatim; OUTPUT phase remapped: each wave writes 2 rows x 512 B
//   contiguous segments instead of 16 rows x 128 B — 4x wider HBM segments).
// Blocks 3072..5119: X fp32 -> Xw bf16, grid-stride x4, loads batched.
// Fusion removes one kernel-launch serialization (the two jobs overlap).
#define DQ_BLOCKS 3072
#define XC_BLOCKS 2048

__global__ void __launch_bounds__(256)
prep(const int* __restrict__ Q, const float* __restrict__ S,
     const float* __restrict__ Z, unsigned short* __restrict__ Wt,
     const float* __restrict__ X, unsigned short* __restrict__ Xw)
{
    const int t = threadIdx.x;
    if (blockIdx.x < DQ_BLOCKS) {
        // ---------------- dequant + transpose ----------------
        __shared__ unsigned short Ls[4][64][72];     // 36.9 KB
        const int b     = blockIdx.x;
        const int kbase = (b & 15) * 256;            // k-block 0..15
        const int n0    = (b >> 4) * 64;             // n-block 0..191
        const int tn = t & 15, tk = t >> 4;
        const int nc = tn * 4;

        floatx4 s4[4], z4[4];
        intx4 q[4][4];
        #pragma unroll
        for (int s = 0; s < 4; ++s) {
            const int k0 = kbase + s * 64;
            const int g  = k0 >> 6;                  // GROUP == 64
            s4[s] = *reinterpret_cast<const floatx4*>(&S[(size_t)g * Ndim + n0 + nc]);
            z4[s] = *reinterpret_cast<const floatx4*>(&Z[(size_t)g * Ndim + n0 + nc]);
            #pragma unroll
            for (int r = 0; r < 4; ++r)
                q[s][r] = *reinterpret_cast<const intx4*>(
                    &Q[(size_t)(k0 + tk * 4 + r) * Ndim + n0 + nc]);
        }
        #pragma unroll
        for (int s = 0; s < 4; ++s) {
            #pragma unroll
            for (int j = 0; j < 4; ++j) {
                const float sv = s4[s][j], zv = z4[s][j];
                ushortx4 w;
                w.x = f2bf(fmaf((float)q[s][0][j], sv, zv));
                w.y = f2bf(fmaf((float)q[s][1][j], sv, zv));
                w.z = f2bf(fmaf((float)q[s][2][j], sv, zv));
                w.w = f2bf(fmaf((float)q[s][3][j], sv, zv));
                *reinterpret_cast<ushortx4*>(&Ls[s][nc + j][tk * 4]) = w;
            }
        }
        __syncthreads();
        // output: thread t -> row (t>>5)+8p, 16 B at k-offset (t&31)*8.
        // 32 consecutive lanes cover one full 512 B row segment.
        const int n_o = t >> 5;                      // 0..7
        const int ko  = (t & 31) * 8;                // 0..248
        const int so  = ko >> 6;                     // stage
        const int kc  = ko & 63;
        #pragma unroll
        for (int p = 0; p < 8; ++p) {
            const int n = n_o + p * 8;
            const ushortx8 v = *reinterpret_cast<const ushortx8*>(&Ls[so][n][kc]);
            *reinterpret_cast<ushortx8*>(
                &Wt[(size_t)(n0 + n) * Kdim + kbase + ko]) = v;
        }
    } else {
        // ---------------- xconv (grid-stride x4, batched loads) ----------------
        const int xb = blockIdx.x - DQ_BLOCKS;       // 0..2047
        const size_t stride = (size_t)XC_BLOCKS * 256 * 8;
        size_t base = ((size_t)xb * 256 + t) * 8;
        floatx4 a[4], b2[4];
        #pragma unroll
        for (int it = 0; it < 4; ++it) {
            a[it]  = *reinterpret_cast<const floatx4*>(&X[base + it * stride]);
            b2[it] = *reinterpret_cast<const floatx4*>(&X[base + it * stride + 4]);
        }
        #pragma unroll
        for (int it = 0; it < 4; ++it) {
            ushortx8 w;
            w[0] = f2bf(a[it].x); w[1] = f2bf(a[it].y);
            w[2] = f2bf(a[it].z); w[3] = f2bf(a[it].w);
            w[4] = f2bf(b2[it].x); w[5] = f2bf(b2[it].y);
            w[6] = f2bf(b2[it].z); w[7] = f2bf(b2[it].w);
            *reinterpret_cast<ushortx8*>(&Xw[base + it * stride]) = w;
        }
    }
}

// ---------------- Main GEMM: 256x256x64, 8-wave, rotated pre-read (R2) -------
// Best verified schedule (422-430 us, MfmaUtil 43-44%). Deep-drain variants
// (R6) were correct but slower -> stall is LDS port/sync machinery, not vmcnt
// latency; keep R2.

#define STAGE_A(c, kt, h) do { \
    const unsigned short* sp_ = A + aoff + (size_t)((h) * 128) * Kdim + (size_t)(kt) * 64; \
    unsigned short* dp_ = &As[c][((h) * 128 + wave * 16) * 64]; \
    gload_lds16(sp_, dp_); \
    gload_lds16(sp_ + (size_t)8 * Kdim, dp_ + 8 * 64); \
} while (0)

#define STAGE_B(c, kt, h) do { \
    const unsigned short* sp_ = B + boff + (size_t)((h) * 128) * Kdim + (size_t)(kt) * 64; \
    unsigned short* dp_ = &Bs[c][((h) * 128 + wave * 16) * 64]; \
    gload_lds16(sp_, dp_); \
    gload_lds16(sp_ + (size_t)8 * Kdim, dp_ + 8 * 64); \
} while (0)

#define LDA_(c, i, kh) (*reinterpret_cast<const short8*>( \
    &As[c][(wm + (i) * 16 + lrow) * 64 + (((kh) * 4 + quad) ^ lsw) * 8]))
#define LDB_(c, j, kh) (*reinterpret_cast<const short8*>( \
    &Bs[c][(wn + (j) * 16 + lrow) * 64 + (((kh) * 4 + quad) ^ lsw) * 8]))

#define SBAR()  __builtin_amdgcn_sched_barrier(0)

// 16 MFMA: all 8 k-half-0 first (independent), then 8 k-half-1 (dep distance 8)
#define MFMA_Q(AF, BF, IO, JO) do { \
    __builtin_amdgcn_s_setprio(1); \
    _Pragma("unroll") \
    for (int kh_ = 0; kh_ < 2; ++kh_) { \
        _Pragma("unroll") \
        for (int i_ = 0; i_ < 4; ++i_) { \
            _Pragma("unroll") \
            for (int j_ = 0; j_ < 2; ++j_) { \
                acc[(IO) + i_][(JO) + j_] = __builtin_amdgcn_mfma_f32_16x16x32_bf16( \
                    AF[i_][kh_], BF[j_][kh_], acc[(IO) + i_][(JO) + j_], 0, 0, 0); \
            } \
        } \
    } \
    __builtin_amdgcn_s_setprio(0); \
} while (0)

__global__ void __launch_bounds__(512, 2)
gemm_bf16_8p(const unsigned short* __restrict__ A, const unsigned short* __restrict__ B,
             const float* __restrict__ bias, float* __restrict__ O)
{
    __shared__ unsigned short As[2][256 * 64];   // 64 KiB
    __shared__ unsigned short Bs[2][256 * 64];   // 64 KiB

    constexpr int NT = Kdim / 64;                // 64 K-tiles

    // XCD-aware bijective swizzle (768 % 8 == 0), then 8-row-band grouping
    const int nblk = Ndim / 256;                 // 48
    const int cpx  = (Mdim / 256) * nblk / 8;    // 96 blocks per XCD
    const int bid  = blockIdx.x;
    const int swz  = (bid & 7) * cpx + (bid >> 3);
    const int gsz  = 8 * nblk;                   // 384
    const int grp  = swz / gsz;
    const int r    = swz % gsz;
    const int m0   = (grp * 8 + (r & 7)) * 256;
    const int n0   = (r >> 3) * 256;

    const int t    = threadIdx.x;
    const int wave = t >> 6;                     // 0..7
    const int lane = t & 63;
    const int wm   = (wave >> 2) * 128;          // 128-row half
    const int wn   = (wave & 3) * 64;            // 64-col quarter
    const int lrow = lane & 15;
    const int quad = lane >> 4;
    const int lsw  = lrow & 7;

    // staging: lane fills physical chunk (lane&7) of row (lane>>3) in an 8-row slab;
    // that chunk must hold logical k-chunk (lane&7)^(row&7)
    const int srow = lane >> 3;
    const int scol = ((lane & 7) ^ srow) * 8;
    const size_t aoff = (size_t)(m0 + wave * 16 + srow) * Kdim + scol;
    const size_t boff = (size_t)(n0 + wave * 16 + srow) * Kdim + scol;

    floatx4 acc[8][4];
    #pragma unroll
    for (int i = 0; i < 8; ++i)
        #pragma unroll
        for (int j = 0; j < 4; ++j)
            acc[i][j] = floatx4{0.f, 0.f, 0.f, 0.f};

    short8 afA[4][2];   // A-M0 frags of current tile
    short8 afB[4][2];   // A-M1 frags
    short8 bA[2][2];    // B-N01 frags
    short8 bB[2][2];    // B-N23 frags

    // -------- prologue: stage A0,B0 (buf0), B1 (buf1), A1h0 (buf1) ----------
    STAGE_A(0, 0, 0); STAGE_A(0, 0, 1);
    STAGE_B(0, 0, 0); STAGE_B(0, 0, 1);
    STAGE_B(1, 1, 0); STAGE_B(1, 1, 1);
    STAGE_A(1, 1, 0);
    asm volatile("s_waitcnt vmcnt(2)" ::: "memory");   // A0,B0,B1 done; A1h0 in flight
    __builtin_amdgcn_s_barrier();
    SBAR();
    #pragma unroll
    for (int i = 0; i < 4; ++i) { afA[i][0] = LDA_(0, i, 0); afA[i][1] = LDA_(0, i, 1); }
    #pragma unroll
    for (int j = 0; j < 2; ++j) { bA[j][0] = LDB_(0, j, 0); bA[j][1] = LDB_(0, j, 1); }
    #pragma unroll
    for (int j = 0; j < 2; ++j) { bB[j][0] = LDB_(0, j + 2, 0); bB[j][1] = LDB_(0, j + 2, 1); }
    asm volatile("s_waitcnt lgkmcnt(0)" ::: "memory");
    SBAR();
    __builtin_amdgcn_s_barrier();
    SBAR();

    for (int u = 0; u < NT; ++u) {
        const int c = u & 1, cn = c ^ 1;

        // ---- phi1: read afB(c); stage A(u+1)h1 then B(u+2)h0; MFMA Q1 ----
        #pragma unroll
        for (int i = 0; i < 4; ++i) { afB[i][0] = LDA_(c, i + 4, 0); afB[i][1] = LDA_(c, i + 4, 1); }
        if (u + 1 < NT) STAGE_A(cn, u + 1, 1);
        if (u + 2 < NT) STAGE_B(c, u + 2, 0);
        MFMA_Q(afA, bA, 0, 0);
        SBAR();
        __builtin_amdgcn_s_barrier();
        SBAR();

        // ---- phi2: stage B(u+2)h1; MFMA Q2; counted vmcnt; barrier ----
        if (u + 2 < NT) STAGE_B(c, u + 2, 1);
        MFMA_Q(afB, bA, 4, 0);
        SBAR();
        if (u < NT - 2) { asm volatile("s_waitcnt vmcnt(4)" ::: "memory"); }
        else            { asm volatile("s_waitcnt vmcnt(0)" ::: "memory"); }
        __builtin_amdgcn_s_barrier();
        SBAR();

        // ---- phi3: pre-read bA'(u+1); MFMA Q3 ----
        if (u + 1 < NT) {
            #pragma unroll
            for (int j = 0; j < 2; ++j) { bA[j][0] = LDB_(cn, j, 0); bA[j][1] = LDB_(cn, j, 1); }
        }
        MFMA_Q(afA, bB, 0, 2);
        SBAR();
        __builtin_amdgcn_s_barrier();
        SBAR();

        // ---- phi4: pre-read afA'(u+1); stage A(u+2)h0; MFMA Q4; THEN read bB'; drain ----
        if (u + 1 < NT) {
            #pragma unroll
            for (int i = 0; i < 4; ++i) { afA[i][0] = LDA_(cn, i, 0); afA[i][1] = LDA_(cn, i, 1); }
        }
        if (u + 2 < NT) STAGE_A(c, u + 2, 0);
        MFMA_Q(afB, bB, 4, 2);
        SBAR();
        if (u + 1 < NT) {
            #pragma unroll
            for (int j = 0; j < 2; ++j) { bB[j][0] = LDB_(cn, j + 2, 0); bB[j][1] = LDB_(cn, j + 2, 1); }
        }
        asm volatile("s_waitcnt lgkmcnt(0)" ::: "memory");
        SBAR();
        __builtin_amdgcn_s_barrier();
        SBAR();
    }

    // -------- epilogue --------
    #pragma unroll
    for (int j = 0; j < 4; ++j) {
        const int col = n0 + wn + j * 16 + lrow;
        const float bv = bias[col];
        #pragma unroll
        for (int i = 0; i < 8; ++i) {
            const int rbase = m0 + wm + i * 16 + quad * 4;
            #pragma unroll
            for (int rr = 0; rr < 4; ++rr)
                O[(size_t)(rbase + rr) * Ndim + col] = acc[i][j][rr] + bv;
        }
    }
}

// ---------------- Fallback (fused, ws-independent) ---------------------------
__global__ void __launch_bounds__(256)
w2a16_gemm_fb(const float* __restrict__ X, const int* __restrict__ Q,
              const float* __restrict__ S, const float* __restrict__ Z,
              const float* __restrict__ bias, float* __restrict__ O)
{
    __shared__ unsigned short Asf[128][72];
    __shared__ unsigned short Bsf[128][72];
    const int t  = threadIdx.x;
    const int n0 = blockIdx.x * 128;
    const int m0 = blockIdx.y * 128;
    const int wave = t >> 6, lane = t & 63;
    const int wm = (wave & 1) * 64, wn = (wave >> 1) * 64;
    const int lrow = lane & 15, quad = lane >> 4;
    floatx4 acc[4][4];
    #pragma unroll
    for (int i = 0; i < 4; ++i)
        #pragma unroll
        for (int j = 0; j < 4; ++j) acc[i][j] = floatx4{0.f, 0.f, 0.f, 0.f};
    const int a_row0 = t >> 4, a_c = (t & 15) * 4;
    const int b_n = t & 127, b_k0 = (t >> 7) * 32;
    for (int k0 = 0; k0 < Kdim; k0 += 64) {
        #pragma unroll
        for (int i = 0; i < 8; ++i) {
            const int row = a_row0 + i * 16;
            const floatx4 v = *reinterpret_cast<const floatx4*>(
                &X[(size_t)(m0 + row) * Kdim + k0 + a_c]);
            ushortx4 w;
            w.x = f2bf(v.x); w.y = f2bf(v.y); w.z = f2bf(v.z); w.w = f2bf(v.w);
            *reinterpret_cast<ushortx4*>(&Asf[row][a_c]) = w;
        }
        const int g = k0 >> 6;
        const float s = S[(size_t)g * Ndim + n0 + b_n];
        const float z = Z[(size_t)g * Ndim + n0 + b_n];
        #pragma unroll
        for (int i = 0; i < 8; ++i) {
            const int kk = b_k0 + i * 4;
            const int* qp = &Q[(size_t)(k0 + kk) * Ndim + n0 + b_n];
            ushortx4 w;
            w.x = f2bf(fmaf((float)qp[0],                s, z));
            w.y = f2bf(fmaf((float)qp[(size_t)Ndim],     s, z));
            w.z = f2bf(fmaf((float)qp[(size_t)2 * Ndim], s, z));
            w.w = f2bf(fmaf((float)qp[(size_t)3 * Ndim], s, z));
            *reinterpret_cast<ushortx4*>(&Bsf[b_n][kk]) = w;
        }
        __syncthreads();
        #pragma unroll
        for (int kk = 0; kk < 64; kk += 32) {
            short8 afv[4], bfv[4];
            #pragma unroll
            for (int i = 0; i < 4; ++i)
                afv[i] = *reinterpret_cast<const short8*>(&Asf[wm + i * 16 + lrow][kk + quad * 8]);
            #pragma unroll
            for (int j = 0; j < 4; ++j)
                bfv[j] = *reinterpret_cast<const short8*>(&Bsf[wn + j * 16 + lrow][kk + quad * 8]);
            #pragma unroll
            for (int i = 0; i < 4; ++i)
                #pragma unroll
                for (int j = 0; j < 4; ++j)
                    acc[i][j] = __builtin_amdgcn_mfma_f32_16x16x32_bf16(afv[i], bfv[j], acc[i][j], 0, 0, 0);
        }
        __syncthreads();
    }
    #pragma unroll
    for (int j = 0; j < 4; ++j) {
        const int col = n0 + wn + j * 16 + lrow;
        const float bv = bias[col];
        #pragma unroll
        for (int i = 0; i < 4; ++i) {
            const int rbase = m0 + wm + i * 16 + quad * 4;
            #pragma unroll
            for (int rr = 0; rr < 4; ++rr)
                O[(size_t)(rbase + rr) * Ndim + col] = acc[i][j][rr] + bv;
        }
    }
}

extern "C" void kernel_launch(void* const* d_in, const int* in_sizes, int n_in,
                              void* d_out, int out_size, void* d_ws, size_t ws_size,
                              hipStream_t stream) {
    const float* X  = (const float*)d_in[0];
    const int*   Q  = (const int*)d_in[1];
    const float* S  = (const float*)d_in[2];
    const float* Z  = (const float*)d_in[3];
    const float* Bi = (const float*)d_in[4];
    float* O = (float*)d_out;

    const size_t wt_bytes = (size_t)Kdim * Ndim * 2;
    const size_t xw_bytes = (size_t)Mdim * Kdim * 2;

    if (ws_size >= wt_bytes + xw_bytes) {
        unsigned short* Wt = (unsigned short*)d_ws;
        unsigned short* Xw = (unsigned short*)((char*)d_ws + wt_bytes);

        hipLaunchKernelGGL(prep, dim3(DQ_BLOCKS + XC_BLOCKS), dim3(256), 0, stream,
                           Q, S, Z, Wt, X, Xw);

        const int nblocks = (Mdim / 256) * (Ndim / 256);  // 768
        hipLaunchKernelGGL(gemm_bf16_8p, dim3(nblocks), dim3(512), 0, stream, Xw, Wt, Bi, O);
    } else {
        dim3 grid(Ndim / 128, Mdim / 128);
        hipLaunchKernelGGL(w2a16_gemm_fb, grid, dim3(256), 0, stream, X, Q, S, Z, Bi, O);
    }
}